// Round 2
// baseline (394.550 us; speedup 1.0000x reference)
//
#include <hip/hip_runtime.h>
#include <hip/hip_bf16.h>

#define N_NODES 50000
#define N_EDGES 800000
#define F_IN    128
#define HC      128      // H*C
#define NPB     16       // nodes per block in k_linear
#define KC      32       // K-chunk in k_linear

// ---------------------------------------------------------------------------
// K1: h = x@Wg ; z0 = bias + 0.1*(x@Ws) ; a_src/a_dst per-head attention dots
// 256 threads, 16 nodes/block; thread t: node=t>>4, cols c0=(t&15)*8 .. +7.
// W staged in LDS in K-chunks of 32 (34 KiB total LDS).
// ---------------------------------------------------------------------------
__global__ __launch_bounds__(256) void k_linear(
    const float* __restrict__ x,
    const float* __restrict__ Wg,
    const float* __restrict__ Ws,
    const float* __restrict__ att_s,
    const float* __restrict__ att_d,
    const float* __restrict__ bias,
    float* __restrict__ h, float* __restrict__ z0,
    float* __restrict__ a_src, float* __restrict__ a_dst)
{
    __shared__ float sWg[KC * HC];   // 16 KiB
    __shared__ float sWs[KC * HC];   // 16 KiB
    __shared__ float sx[NPB * KC];   // 2 KiB
    const int tid = threadIdx.x;
    const int node = tid >> 4;
    const int c0 = (tid & 15) * 8;
    const int gn = blockIdx.x * NPB + node;

    float accg[8] = {0, 0, 0, 0, 0, 0, 0, 0};
    float accs[8] = {0, 0, 0, 0, 0, 0, 0, 0};

    for (int kc = 0; kc < F_IN; kc += KC) {
        __syncthreads();   // previous chunk's compute done before overwrite
        // stage W chunks (rows kc..kc+31 are contiguous: 4096 floats each)
        for (int i = tid * 4; i < KC * HC; i += 256 * 4) {
            *(float4*)(sWg + i) = *(const float4*)(Wg + kc * HC + i);
            *(float4*)(sWs + i) = *(const float4*)(Ws + kc * HC + i);
        }
        // stage x chunk: 16 nodes x 32 k
        if (tid < 128) {
            const int n = tid >> 3;
            const int k4 = (tid & 7) * 4;
            *(float4*)(sx + n * KC + k4) =
                *(const float4*)(x + (size_t)(blockIdx.x * NPB + n) * F_IN + kc + k4);
        }
        __syncthreads();

#pragma unroll 8
        for (int kk = 0; kk < KC; kk++) {
            const float xv = sx[node * KC + kk];
            const float* wg = sWg + kk * HC + c0;
            const float* ws = sWs + kk * HC + c0;
#pragma unroll
            for (int j = 0; j < 8; j++) {
                accg[j] += xv * wg[j];
                accs[j] += xv * ws[j];
            }
        }
    }

    // attention dots: att flat index head*16 + c == c0+j exactly
    float psrc = 0.f, pdst = 0.f;
#pragma unroll
    for (int j = 0; j < 8; j++) {
        psrc += accg[j] * att_s[c0 + j];
        pdst += accg[j] * att_d[c0 + j];
    }
    psrc += __shfl_xor(psrc, 1);
    pdst += __shfl_xor(pdst, 1);
    if ((tid & 1) == 0) {
        const int head = c0 >> 4;
        a_src[gn * 8 + head] = psrc;
        a_dst[gn * 8 + head] = pdst;
    }

    *(float4*)(h + (size_t)gn * HC + c0)     = make_float4(accg[0], accg[1], accg[2], accg[3]);
    *(float4*)(h + (size_t)gn * HC + c0 + 4) = make_float4(accg[4], accg[5], accg[6], accg[7]);
    float zb[8];
#pragma unroll
    for (int j = 0; j < 8; j++) zb[j] = 0.1f * accs[j] + bias[c0 + j];
    *(float4*)(z0 + (size_t)gn * HC + c0)     = make_float4(zb[0], zb[1], zb[2], zb[3]);
    *(float4*)(z0 + (size_t)gn * HC + c0 + 4) = make_float4(zb[4], zb[5], zb[6], zb[7]);
}

// ---------------------------------------------------------------------------
// CSR build: counts (init 1 for self-loop) -> exclusive scan -> cursor fill
// ---------------------------------------------------------------------------
__global__ void k_init(int* __restrict__ counts) {
    int i = blockIdx.x * 256 + threadIdx.x;
    if (i < N_NODES) counts[i] = 1;
}

__global__ void k_count(const int* __restrict__ dst, int* counts) {
    int i = blockIdx.x * 256 + threadIdx.x;
    if (i < N_EDGES) atomicAdd(&counts[dst[i]], 1);
}

__global__ __launch_bounds__(256) void k_scanA(const int* __restrict__ counts,
                                               int* __restrict__ row_start,
                                               int* __restrict__ bsum) {
    __shared__ int s[256];
    const int tid = threadIdx.x;
    const int base = blockIdx.x * 1024 + tid * 4;
    int v[4]; int t = 0;
#pragma unroll
    for (int j = 0; j < 4; j++) {
        int idx = base + j;
        v[j] = (idx < N_NODES) ? counts[idx] : 0;
        t += v[j];
    }
    s[tid] = t;
    __syncthreads();
    for (int off = 1; off < 256; off <<= 1) {
        int add = (tid >= off) ? s[tid - off] : 0;
        __syncthreads();
        s[tid] += add;
        __syncthreads();
    }
    int excl = s[tid] - t;
#pragma unroll
    for (int j = 0; j < 4; j++) {
        int idx = base + j;
        if (idx < N_NODES) row_start[idx] = excl;
        excl += v[j];
    }
    if (tid == 255) bsum[blockIdx.x] = s[255];
}

__global__ void k_scanB(int* bsum, int nb) {
    int tid = threadIdx.x;   // 64 threads, nb <= 64
    int v = (tid < nb) ? bsum[tid] : 0;
    int orig = v;
    for (int off = 1; off < 64; off <<= 1) {
        int y = __shfl_up(v, off);
        if (tid >= off) v += y;
    }
    if (tid < nb) bsum[tid] = v - orig;   // exclusive block offsets
}

__global__ void k_scanC(int* __restrict__ row_start, const int* __restrict__ bsum,
                        int* __restrict__ cursor) {
    int i = blockIdx.x * 256 + threadIdx.x;
    if (i < N_NODES) {
        int rs = row_start[i] + bsum[i >> 10];
        row_start[i] = rs;
        cursor[i] = rs;
    }
}

__global__ void k_fill(const int* __restrict__ src, const int* __restrict__ dst,
                       int* cursor, int* __restrict__ csr) {
    int i = blockIdx.x * 256 + threadIdx.x;
    if (i >= N_EDGES + N_NODES) return;
    int s, d;
    if (i < N_EDGES) { s = src[i]; d = dst[i]; }
    else             { s = d = i - N_EDGES; }   // self-loops
    int slot = atomicAdd(&cursor[d], 1);
    csr[slot] = s;
}

// ---------------------------------------------------------------------------
// K5: per-node aggregation (softmax-normalized message sum) + skip + LN + ELU
// one wave (64 lanes) per node, 2 cols/lane; block 256 = 4 nodes.
// softmax max-subtraction cancels in (sum w*h)/(sum w) — skipped on purpose;
// |e| <= ~6 so exp() cannot overflow.
// ---------------------------------------------------------------------------
__global__ __launch_bounds__(256) void k_agg(
    const float* __restrict__ h, const float* __restrict__ z0,
    const float* __restrict__ a_src, const float* __restrict__ a_dst,
    const int* __restrict__ row_start, const int* __restrict__ counts,
    const int* __restrict__ csr,
    const float* __restrict__ gamma, const float* __restrict__ beta,
    float* __restrict__ out)
{
    const int tid = threadIdx.x;
    const int lane = tid & 63;
    const int n = blockIdx.x * 4 + (tid >> 6);
    const int head = lane >> 3;           // cols 2*lane, 2*lane+1 -> head = lane>>3

    const float adn = a_dst[n * 8 + head];
    const int rs = row_start[n];
    const int cnt = counts[n];

    float d_acc = 0.f, a0 = 0.f, a1 = 0.f;
    const float2* h2 = (const float2*)h;
    for (int i = 0; i < cnt; i++) {
        const int s = csr[rs + i];
        float e = a_src[s * 8 + head] + adn;
        e = (e > 0.f) ? e : 0.2f * e;      // leaky_relu(0.2)
        const float w = __expf(e);
        d_acc += w;
        const float2 hv = h2[(size_t)s * 64 + lane];
        a0 += w * hv.x;
        a1 += w * hv.y;
    }
    const float inv = 1.0f / d_acc;
    const float2 zv = ((const float2*)z0)[(size_t)n * 64 + lane];
    float y0 = a0 * inv + zv.x;
    float y1 = a1 * inv + zv.y;

    // LayerNorm over 128 cols (wave-wide)
    float ssum = y0 + y1;
#pragma unroll
    for (int off = 1; off < 64; off <<= 1) ssum += __shfl_xor(ssum, off);
    const float mu = ssum * (1.0f / 128.0f);
    const float d0 = y0 - mu, d1 = y1 - mu;
    float vs = d0 * d0 + d1 * d1;
#pragma unroll
    for (int off = 1; off < 64; off <<= 1) vs += __shfl_xor(vs, off);
    const float rstd = rsqrtf(vs * (1.0f / 128.0f) + 1e-5f);

    const int c = lane * 2;
    float o0 = d0 * rstd * gamma[c]     + beta[c];
    float o1 = d1 * rstd * gamma[c + 1] + beta[c + 1];
    o0 = (o0 > 0.f) ? o0 : (__expf(o0) - 1.0f);   // ELU
    o1 = (o1 > 0.f) ? o1 : (__expf(o1) - 1.0f);

    ((float2*)out)[(size_t)n * 64 + lane] = make_float2(o0, o1);
}

// ---------------------------------------------------------------------------
extern "C" void kernel_launch(void* const* d_in, const int* in_sizes, int n_in,
                              void* d_out, int out_size, void* d_ws, size_t ws_size,
                              hipStream_t stream) {
    const float* x   = (const float*)d_in[0];
    const int*   ei  = (const int*)d_in[1];
    const float* Wg  = (const float*)d_in[2];
    const float* as_ = (const float*)d_in[3];
    const float* ad_ = (const float*)d_in[4];
    const float* bg  = (const float*)d_in[5];
    const float* Wsk = (const float*)d_in[6];
    const float* gm  = (const float*)d_in[7];
    const float* bt  = (const float*)d_in[8];
    float* out = (float*)d_out;

    // workspace layout (fp32/int32 elements), ~58.4 MB
    float* h      = (float*)d_ws;                 // 6.4M
    float* z0     = h + 6400000;                  // 6.4M
    float* a_src  = z0 + 6400000;                 // 0.4M
    float* a_dst  = a_src + 400000;               // 0.4M
    int*   counts = (int*)(a_dst + 400000);       // 50048
    int*   row_st = counts + 50048;               // 50048
    int*   cursor = row_st + 50048;               // 50048
    int*   bsum   = cursor + 50048;               // 256
    int*   csr    = bsum + 256;                   // 850000

    const int* src = ei;
    const int* dst = ei + N_EDGES;

    k_linear<<<N_NODES / NPB, 256, 0, stream>>>(x, Wg, Wsk, as_, ad_, bg, h, z0, a_src, a_dst);
    k_init  <<<(N_NODES + 255) / 256, 256, 0, stream>>>(counts);
    k_count <<<(N_EDGES + 255) / 256, 256, 0, stream>>>(dst, counts);
    k_scanA <<<49, 256, 0, stream>>>(counts, row_st, bsum);
    k_scanB <<<1, 64, 0, stream>>>(bsum, 49);
    k_scanC <<<(N_NODES + 255) / 256, 256, 0, stream>>>(row_st, bsum, cursor);
    k_fill  <<<(N_EDGES + N_NODES + 255) / 256, 256, 0, stream>>>(src, dst, cursor, csr);
    k_agg   <<<N_NODES / 4, 256, 0, stream>>>(h, z0, a_src, a_dst, row_st, counts, csr, gm, bt, out);
}

// Round 3
// 323.236 us; speedup vs baseline: 1.2206x; 1.2206x over previous
//
#include <hip/hip_runtime.h>
#include <hip/hip_bf16.h>

#define N_NODES 50000
#define N_EDGES 800000
#define F_IN    128
#define HC      128      // H*C

typedef __attribute__((ext_vector_type(8))) short bf16x8;
typedef __attribute__((ext_vector_type(4))) float f32x4;

__device__ __forceinline__ float bf2f(unsigned int u16) {
    return __uint_as_float(u16 << 16);
}
__device__ __forceinline__ unsigned int f2bf(float f) {
    unsigned int u = __float_as_uint(f);
    return (u + 0x7fffu + ((u >> 16) & 1u)) >> 16;   // RNE
}

// ---------------------------------------------------------------------------
// K1 (MFMA): h_bf16 = x@Wg ; z0 = bias + 0.1*(x@Ws) ; a_src/a_dst att dots.
// 256 threads = 4 waves; 64 nodes/block; K=128; cols 0..255 = [Wg | Ws].
// Wave w owns cols [w*64, w*64+64) as 4 n-tiles; 4 m-tiles of 16 rows.
// LDS holds A (16 KB) and B (64 KB) in fragment-major order: frag reads are
// lane-linear 16B -> conflict-free.
// ---------------------------------------------------------------------------
__global__ __launch_bounds__(256) void k_linear(
    const float* __restrict__ x,
    const float* __restrict__ Wg,
    const float* __restrict__ Ws,
    const float* __restrict__ att_s,
    const float* __restrict__ att_d,
    const float* __restrict__ bias,
    unsigned short* __restrict__ h_bf, float* __restrict__ z0,
    float* __restrict__ a_src, float* __restrict__ a_dst)
{
    __shared__ unsigned short sA[16 * 64 * 8];   // [mt*4+kq][lane][j]  16 KB
    __shared__ unsigned short sB[64 * 64 * 8];   // [nt*4+kq][lane][j]  64 KB
    const int tid = threadIdx.x;
    const int lane = tid & 63;
    const int w = tid >> 6;
    const int nbase = blockIdx.x * 64;

    // ---- stage A: x[64 nodes][128 k] -> bf16 fragment-major ----
#pragma unroll
    for (int it = 0; it < 4; it++) {
        const int p = it * 256 + tid;
        const int node = p >> 4;        // 0..63
        const int kg = p & 15;          // k-group of 8
        const int gn = nbase + node;
        float v[8];
        if (gn < N_NODES) {
            float4 u0 = *(const float4*)(x + (size_t)gn * F_IN + kg * 8);
            float4 u1 = *(const float4*)(x + (size_t)gn * F_IN + kg * 8 + 4);
            v[0] = u0.x; v[1] = u0.y; v[2] = u0.z; v[3] = u0.w;
            v[4] = u1.x; v[5] = u1.y; v[6] = u1.z; v[7] = u1.w;
        } else {
#pragma unroll
            for (int j = 0; j < 8; j++) v[j] = 0.f;
        }
        const int mt = node >> 4, lm = node & 15;
        const int kq = kg >> 2, quad = kg & 3;
        uint4 pk;
        pk.x = f2bf(v[0]) | (f2bf(v[1]) << 16);
        pk.y = f2bf(v[2]) | (f2bf(v[3]) << 16);
        pk.z = f2bf(v[4]) | (f2bf(v[5]) << 16);
        pk.w = f2bf(v[6]) | (f2bf(v[7]) << 16);
        *(uint4*)(sA + ((size_t)((mt * 4 + kq) * 64 + quad * 16 + lm)) * 8) = pk;
    }

    // ---- stage B: [Wg|Ws][128 k][256 cols] -> bf16 fragment-major ----
#pragma unroll 4
    for (int kg = 0; kg < 16; kg++) {
        const int c = tid;              // 0..255 column
        const int k0 = kg * 8;
        const float* Wsel = (c < 128) ? (Wg + c) : (Ws + c - 128);
        float v[8];
#pragma unroll
        for (int j = 0; j < 8; j++) v[j] = Wsel[(size_t)(k0 + j) * HC];
        const int nt = c >> 4, ln = c & 15;
        const int kq = kg >> 2, quad = kg & 3;
        uint4 pk;
        pk.x = f2bf(v[0]) | (f2bf(v[1]) << 16);
        pk.y = f2bf(v[2]) | (f2bf(v[3]) << 16);
        pk.z = f2bf(v[4]) | (f2bf(v[5]) << 16);
        pk.w = f2bf(v[6]) | (f2bf(v[7]) << 16);
        *(uint4*)(sB + ((size_t)((nt * 4 + kq) * 64 + quad * 16 + ln)) * 8) = pk;
    }
    __syncthreads();

    // ---- MFMA main loop ----
    f32x4 acc[4][4];
#pragma unroll
    for (int mt = 0; mt < 4; mt++)
#pragma unroll
        for (int nt = 0; nt < 4; nt++)
            acc[mt][nt] = (f32x4){0.f, 0.f, 0.f, 0.f};

#pragma unroll
    for (int kq = 0; kq < 4; kq++) {
        bf16x8 aF[4], bF[4];
#pragma unroll
        for (int mt = 0; mt < 4; mt++)
            aF[mt] = *(const bf16x8*)(sA + ((size_t)((mt * 4 + kq) * 64 + lane)) * 8);
#pragma unroll
        for (int nt = 0; nt < 4; nt++)
            bF[nt] = *(const bf16x8*)(sB + ((size_t)(((w * 4 + nt) * 4 + kq) * 64 + lane)) * 8);
#pragma unroll
        for (int mt = 0; mt < 4; mt++)
#pragma unroll
            for (int nt = 0; nt < 4; nt++)
                acc[mt][nt] = __builtin_amdgcn_mfma_f32_16x16x32_bf16(
                    aF[mt], bF[nt], acc[mt][nt], 0, 0, 0);
    }

    // ---- epilogue: D[row=(lane>>4)*4+r][col=lane&15] ----
    const int row4 = (lane >> 4) * 4;
    const int cl = lane & 15;
#pragma unroll
    for (int mt = 0; mt < 4; mt++) {
#pragma unroll
        for (int nt = 0; nt < 4; nt++) {
            const int c = w * 64 + nt * 16 + cl;   // wave-uniform branch below
            f32x4 d = acc[mt][nt];
            if (c < 128) {
                // h (bf16) + attention partial dots; head = c>>4 = w*4+nt
                const float asv = att_s[c];
                const float adv = att_d[c];
                float ps[4], pd[4];
#pragma unroll
                for (int r = 0; r < 4; r++) { ps[r] = d[r] * asv; pd[r] = d[r] * adv; }
#pragma unroll
                for (int m = 1; m <= 8; m <<= 1) {
#pragma unroll
                    for (int r = 0; r < 4; r++) {
                        ps[r] += __shfl_xor(ps[r], m);
                        pd[r] += __shfl_xor(pd[r], m);
                    }
                }
                const int head = w * 4 + nt;
#pragma unroll
                for (int r = 0; r < 4; r++) {
                    const int gn = nbase + mt * 16 + row4 + r;
                    if (gn < N_NODES) {
                        h_bf[(size_t)gn * HC + c] = (unsigned short)f2bf(d[r]);
                        if (cl == 0) {
                            a_src[gn * 8 + head] = ps[r];
                            a_dst[gn * 8 + head] = pd[r];
                        }
                    }
                }
            } else {
                const int cz = c - 128;
                const float bv = bias[cz];
#pragma unroll
                for (int r = 0; r < 4; r++) {
                    const int gn = nbase + mt * 16 + row4 + r;
                    if (gn < N_NODES)
                        z0[(size_t)gn * HC + cz] = 0.1f * d[r] + bv;
                }
            }
        }
    }
}

// ---------------------------------------------------------------------------
// CSR build: counts (init 1 for self-loop) -> exclusive scan -> cursor fill
// ---------------------------------------------------------------------------
__global__ void k_init(int* __restrict__ counts) {
    int i = blockIdx.x * 256 + threadIdx.x;
    if (i < N_NODES) counts[i] = 1;
}

__global__ void k_count(const int* __restrict__ dst, int* counts) {
    int i = blockIdx.x * 256 + threadIdx.x;
    if (i < N_EDGES) atomicAdd(&counts[dst[i]], 1);
}

__global__ __launch_bounds__(256) void k_scanA(const int* __restrict__ counts,
                                               int* __restrict__ row_start,
                                               int* __restrict__ bsum) {
    __shared__ int s[256];
    const int tid = threadIdx.x;
    const int base = blockIdx.x * 1024 + tid * 4;
    int v[4]; int t = 0;
#pragma unroll
    for (int j = 0; j < 4; j++) {
        int idx = base + j;
        v[j] = (idx < N_NODES) ? counts[idx] : 0;
        t += v[j];
    }
    s[tid] = t;
    __syncthreads();
    for (int off = 1; off < 256; off <<= 1) {
        int add = (tid >= off) ? s[tid - off] : 0;
        __syncthreads();
        s[tid] += add;
        __syncthreads();
    }
    int excl = s[tid] - t;
#pragma unroll
    for (int j = 0; j < 4; j++) {
        int idx = base + j;
        if (idx < N_NODES) row_start[idx] = excl;
        excl += v[j];
    }
    if (tid == 255) bsum[blockIdx.x] = s[255];
}

__global__ void k_scanB(int* bsum, int nb) {
    int tid = threadIdx.x;   // 64 threads, nb <= 64
    int v = (tid < nb) ? bsum[tid] : 0;
    int orig = v;
    for (int off = 1; off < 64; off <<= 1) {
        int y = __shfl_up(v, off);
        if (tid >= off) v += y;
    }
    if (tid < nb) bsum[tid] = v - orig;   // exclusive block offsets
}

__global__ void k_scanC(int* __restrict__ row_start, const int* __restrict__ bsum,
                        int* __restrict__ cursor) {
    int i = blockIdx.x * 256 + threadIdx.x;
    if (i < N_NODES) {
        int rs = row_start[i] + bsum[i >> 10];
        row_start[i] = rs;
        cursor[i] = rs;
    }
}

__global__ void k_fill(const int* __restrict__ src, const int* __restrict__ dst,
                       int* cursor, int* __restrict__ csr) {
    int i = blockIdx.x * 256 + threadIdx.x;
    if (i >= N_EDGES + N_NODES) return;
    int s, d;
    if (i < N_EDGES) { s = src[i]; d = dst[i]; }
    else             { s = d = i - N_EDGES; }   // self-loops
    int slot = atomicAdd(&cursor[d], 1);
    csr[slot] = s;
}

// ---------------------------------------------------------------------------
// K5: per-node aggregation (softmax-normalized message sum) + skip + LN + ELU
// one wave per node, 2 cols/lane; h rows gathered as packed bf16 (256 B/row).
// Softmax max-subtraction cancels in (sum w*h)/(sum w); |e| small -> no ovf.
// Software-pipelined: next edge's csr/a_src/h loads issue before current math.
// ---------------------------------------------------------------------------
__global__ __launch_bounds__(256) void k_agg(
    const unsigned int* __restrict__ h32,   // bf16 pairs, [N][64] uints
    const float* __restrict__ z0,
    const float* __restrict__ a_src, const float* __restrict__ a_dst,
    const int* __restrict__ row_start, const int* __restrict__ counts,
    const int* __restrict__ csr,
    const float* __restrict__ gamma, const float* __restrict__ beta,
    float* __restrict__ out)
{
    const int tid = threadIdx.x;
    const int lane = tid & 63;
    const int n = blockIdx.x * 4 + (tid >> 6);
    const int head = lane >> 3;           // cols 2*lane, 2*lane+1

    const float adn = a_dst[n * 8 + head];
    const int rs = row_start[n];
    const int cnt = counts[n];            // >= 1 (self-loop)

    // pipeline stage 0
    int s0 = csr[rs];
    float ae0 = a_src[s0 * 8 + head];
    unsigned int hp0 = h32[(size_t)s0 * 64 + lane];

    float d_acc = 0.f, a0 = 0.f, a1 = 0.f;
    for (int i = 0; i < cnt; i++) {
        const int ni = (i + 1 < cnt) ? (i + 1) : i;
        const int s1 = csr[rs + ni];
        const float ae1 = a_src[s1 * 8 + head];
        const unsigned int hp1 = h32[(size_t)s1 * 64 + lane];

        float e = ae0 + adn;
        e = (e > 0.f) ? e : 0.2f * e;      // leaky_relu(0.2)
        const float wgt = __expf(e);
        d_acc += wgt;
        a0 += wgt * bf2f(hp0 & 0xffffu);
        a1 += wgt * bf2f(hp0 >> 16);

        ae0 = ae1; hp0 = hp1; s0 = s1;
    }
    const float inv = 1.0f / d_acc;
    const float2 zv = ((const float2*)z0)[(size_t)n * 64 + lane];
    float y0 = a0 * inv + zv.x;
    float y1 = a1 * inv + zv.y;

    // LayerNorm over 128 cols (wave-wide)
    float ssum = y0 + y1;
#pragma unroll
    for (int off = 1; off < 64; off <<= 1) ssum += __shfl_xor(ssum, off);
    const float mu = ssum * (1.0f / 128.0f);
    const float d0 = y0 - mu, d1 = y1 - mu;
    float vs = d0 * d0 + d1 * d1;
#pragma unroll
    for (int off = 1; off < 64; off <<= 1) vs += __shfl_xor(vs, off);
    const float rstd = rsqrtf(vs * (1.0f / 128.0f) + 1e-5f);

    const int c = lane * 2;
    float o0 = d0 * rstd * gamma[c]     + beta[c];
    float o1 = d1 * rstd * gamma[c + 1] + beta[c + 1];
    o0 = (o0 > 0.f) ? o0 : (__expf(o0) - 1.0f);   // ELU
    o1 = (o1 > 0.f) ? o1 : (__expf(o1) - 1.0f);

    ((float2*)out)[(size_t)n * 64 + lane] = make_float2(o0, o1);
}

// ---------------------------------------------------------------------------
extern "C" void kernel_launch(void* const* d_in, const int* in_sizes, int n_in,
                              void* d_out, int out_size, void* d_ws, size_t ws_size,
                              hipStream_t stream) {
    const float* x   = (const float*)d_in[0];
    const int*   ei  = (const int*)d_in[1];
    const float* Wg  = (const float*)d_in[2];
    const float* as_ = (const float*)d_in[3];
    const float* ad_ = (const float*)d_in[4];
    const float* bg  = (const float*)d_in[5];
    const float* Wsk = (const float*)d_in[6];
    const float* gm  = (const float*)d_in[7];
    const float* bt  = (const float*)d_in[8];
    float* out = (float*)d_out;

    // workspace layout (bytes): h_bf 12.8MB | z0 25.6MB | a_src 1.6MB |
    // a_dst 1.6MB | int arrays (~3.6MB)  => ~45.2 MB total
    char* wsb = (char*)d_ws;
    unsigned short* h_bf = (unsigned short*)wsb;             // [N][128] bf16
    float* z0     = (float*)(wsb + 12800000);
    float* a_src  = (float*)(wsb + 38400000);
    float* a_dst  = (float*)(wsb + 40000000);
    int*   counts = (int*)(wsb + 41600000);
    int*   row_st = counts + 50048;
    int*   cursor = row_st + 50048;
    int*   bsum   = cursor + 50048;
    int*   csr    = bsum + 256;

    const int* src = ei;
    const int* dst = ei + N_EDGES;

    k_linear<<<(N_NODES + 63) / 64, 256, 0, stream>>>(x, Wg, Wsk, as_, ad_, bg,
                                                      h_bf, z0, a_src, a_dst);
    k_init  <<<(N_NODES + 255) / 256, 256, 0, stream>>>(counts);
    k_count <<<(N_EDGES + 255) / 256, 256, 0, stream>>>(dst, counts);
    k_scanA <<<49, 256, 0, stream>>>(counts, row_st, bsum);
    k_scanB <<<1, 64, 0, stream>>>(bsum, 49);
    k_scanC <<<(N_NODES + 255) / 256, 256, 0, stream>>>(row_st, bsum, cursor);
    k_fill  <<<(N_EDGES + N_NODES + 255) / 256, 256, 0, stream>>>(src, dst, cursor, csr);
    k_agg   <<<N_NODES / 4, 256, 0, stream>>>((const unsigned int*)h_bf, z0,
                                              a_src, a_dst, row_st, counts, csr,
                                              gm, bt, out);
}

// Round 4
// 256.915 us; speedup vs baseline: 1.5357x; 1.2581x over previous
//
#include <hip/hip_runtime.h>
#include <hip/hip_bf16.h>

#define N_NODES 50000
#define N_EDGES 800000
#define F_IN    128
#define HC      128      // H*C

typedef __attribute__((ext_vector_type(8))) short bf16x8;
typedef __attribute__((ext_vector_type(4))) float f32x4;

__device__ __forceinline__ float bf2f(unsigned int u16) {
    return __uint_as_float(u16 << 16);
}
__device__ __forceinline__ unsigned int f2bf(float f) {
    unsigned int u = __float_as_uint(f);
    return (u + 0x7fffu + ((u >> 16) & 1u)) >> 16;   // RNE
}

// ---------------------------------------------------------------------------
// K0: one-time prep. (a) pack [Wg|Ws] into MFMA-B fragment-major bf16 global
// buffer: slot g=(nt*4+kq)*64+lane holds 8 bf16: W[kq*32+(lane>>4)*8+j][nt*16+
// (lane&15)], cols 0..127=Wg, 128..255=Ws. (b) counts[i]=1 (self-loop).
// ---------------------------------------------------------------------------
__global__ __launch_bounds__(256) void k_prep(
    const float* __restrict__ Wg, const float* __restrict__ Ws,
    unsigned short* __restrict__ Bfrag, int* __restrict__ counts)
{
    const int g = blockIdx.x * 256 + threadIdx.x;
    if (g < 4096) {
        const int lane = g & 63;
        const int kq = (g >> 6) & 3;
        const int nt = g >> 8;           // 0..15
        const int c = nt * 16 + (lane & 15);
        const int kbase = kq * 32 + (lane >> 4) * 8;
        const float* Wsel = (c < 128) ? (Wg + c) : (Ws + c - 128);
        unsigned int pk[4];
#pragma unroll
        for (int p = 0; p < 4; p++) {
            const float v0 = Wsel[(size_t)(kbase + 2 * p) * HC];
            const float v1 = Wsel[(size_t)(kbase + 2 * p + 1) * HC];
            pk[p] = f2bf(v0) | (f2bf(v1) << 16);
        }
        *(uint4*)(Bfrag + (size_t)g * 8) = make_uint4(pk[0], pk[1], pk[2], pk[3]);
    }
    if (g < N_NODES) counts[g] = 1;
}

// ---------------------------------------------------------------------------
// K1 (MFMA): h_bf16 = x@Wg ; z0 = bias + 0.1*(x@Ws) ; a_src/a_dst att dots.
// 256 threads = 4 waves; 64 nodes/block; wave w owns cols [w*64,w*64+64).
// A staged in LDS fragment-major (16 KB); B fragments loaded straight from
// the prepacked global buffer into registers (coalesced, L2-resident).
// ---------------------------------------------------------------------------
__global__ __launch_bounds__(256) void k_linear(
    const float* __restrict__ x,
    const unsigned short* __restrict__ Bfrag,
    const float* __restrict__ att_s,
    const float* __restrict__ att_d,
    const float* __restrict__ bias,
    unsigned short* __restrict__ h_bf, float* __restrict__ z0,
    float* __restrict__ a_src, float* __restrict__ a_dst)
{
    __shared__ unsigned short sA[16 * 64 * 8];   // [mt*4+kq][lane][j]  16 KB
    const int tid = threadIdx.x;
    const int lane = tid & 63;
    const int w = tid >> 6;
    const int nbase = blockIdx.x * 64;

    // ---- stage A: x[64 nodes][128 k] -> bf16 fragment-major ----
#pragma unroll
    for (int it = 0; it < 4; it++) {
        const int p = it * 256 + tid;
        const int node = p >> 4;        // 0..63
        const int kg = p & 15;          // k-group of 8
        const int gn = nbase + node;
        float v[8];
        if (gn < N_NODES) {
            float4 u0 = *(const float4*)(x + (size_t)gn * F_IN + kg * 8);
            float4 u1 = *(const float4*)(x + (size_t)gn * F_IN + kg * 8 + 4);
            v[0] = u0.x; v[1] = u0.y; v[2] = u0.z; v[3] = u0.w;
            v[4] = u1.x; v[5] = u1.y; v[6] = u1.z; v[7] = u1.w;
        } else {
#pragma unroll
            for (int j = 0; j < 8; j++) v[j] = 0.f;
        }
        const int mt = node >> 4, lm = node & 15;
        const int kq = kg >> 2, quad = kg & 3;
        uint4 pk;
        pk.x = f2bf(v[0]) | (f2bf(v[1]) << 16);
        pk.y = f2bf(v[2]) | (f2bf(v[3]) << 16);
        pk.z = f2bf(v[4]) | (f2bf(v[5]) << 16);
        pk.w = f2bf(v[6]) | (f2bf(v[7]) << 16);
        *(uint4*)(sA + ((size_t)((mt * 4 + kq) * 64 + quad * 16 + lm)) * 8) = pk;
    }
    __syncthreads();

    // ---- MFMA main loop; B fragments straight from global ----
    const bf16x8* Bf = (const bf16x8*)Bfrag;
    f32x4 acc[4][4];
#pragma unroll
    for (int mt = 0; mt < 4; mt++)
#pragma unroll
        for (int nt = 0; nt < 4; nt++)
            acc[mt][nt] = (f32x4){0.f, 0.f, 0.f, 0.f};

#pragma unroll
    for (int kq = 0; kq < 4; kq++) {
        bf16x8 aF[4], bF[4];
#pragma unroll
        for (int nt = 0; nt < 4; nt++)
            bF[nt] = Bf[(size_t)(((w * 4 + nt) * 4 + kq) * 64 + lane)];
#pragma unroll
        for (int mt = 0; mt < 4; mt++)
            aF[mt] = *(const bf16x8*)(sA + ((size_t)((mt * 4 + kq) * 64 + lane)) * 8);
#pragma unroll
        for (int mt = 0; mt < 4; mt++)
#pragma unroll
            for (int nt = 0; nt < 4; nt++)
                acc[mt][nt] = __builtin_amdgcn_mfma_f32_16x16x32_bf16(
                    aF[mt], bF[nt], acc[mt][nt], 0, 0, 0);
    }

    // ---- epilogue: D[row=(lane>>4)*4+r][col=lane&15] ----
    const int row4 = (lane >> 4) * 4;
    const int cl = lane & 15;
#pragma unroll
    for (int mt = 0; mt < 4; mt++) {
#pragma unroll
        for (int nt = 0; nt < 4; nt++) {
            const int c = w * 64 + nt * 16 + cl;   // wave-uniform branch below
            f32x4 d = acc[mt][nt];
            if (c < 128) {
                const float asv = att_s[c];
                const float adv = att_d[c];
                float ps[4], pd[4];
#pragma unroll
                for (int r = 0; r < 4; r++) { ps[r] = d[r] * asv; pd[r] = d[r] * adv; }
#pragma unroll
                for (int m = 1; m <= 8; m <<= 1) {
#pragma unroll
                    for (int r = 0; r < 4; r++) {
                        ps[r] += __shfl_xor(ps[r], m);
                        pd[r] += __shfl_xor(pd[r], m);
                    }
                }
                const int head = w * 4 + nt;
#pragma unroll
                for (int r = 0; r < 4; r++) {
                    const int gn = nbase + mt * 16 + row4 + r;
                    if (gn < N_NODES) {
                        h_bf[(size_t)gn * HC + c] = (unsigned short)f2bf(d[r]);
                        if (cl == 0) {
                            a_src[gn * 8 + head] = ps[r];
                            a_dst[gn * 8 + head] = pd[r];
                        }
                    }
                }
            } else {
                const int cz = c - 128;
                const float bv = bias[cz];
#pragma unroll
                for (int r = 0; r < 4; r++) {
                    const int gn = nbase + mt * 16 + row4 + r;
                    if (gn < N_NODES)
                        z0[(size_t)gn * HC + cz] = 0.1f * d[r] + bv;
                }
            }
        }
    }
}

// ---------------------------------------------------------------------------
// CSR build: counts -> exclusive scan -> cursor fill
// ---------------------------------------------------------------------------
__global__ void k_count(const int* __restrict__ dst, int* counts) {
    int i = blockIdx.x * 256 + threadIdx.x;
    if (i < N_EDGES) atomicAdd(&counts[dst[i]], 1);
}

__global__ __launch_bounds__(256) void k_scanA(const int* __restrict__ counts,
                                               int* __restrict__ row_start,
                                               int* __restrict__ bsum) {
    __shared__ int s[256];
    const int tid = threadIdx.x;
    const int base = blockIdx.x * 1024 + tid * 4;
    int v[4]; int t = 0;
#pragma unroll
    for (int j = 0; j < 4; j++) {
        int idx = base + j;
        v[j] = (idx < N_NODES) ? counts[idx] : 0;
        t += v[j];
    }
    s[tid] = t;
    __syncthreads();
    for (int off = 1; off < 256; off <<= 1) {
        int add = (tid >= off) ? s[tid - off] : 0;
        __syncthreads();
        s[tid] += add;
        __syncthreads();
    }
    int excl = s[tid] - t;
#pragma unroll
    for (int j = 0; j < 4; j++) {
        int idx = base + j;
        if (idx < N_NODES) row_start[idx] = excl;
        excl += v[j];
    }
    if (tid == 255) bsum[blockIdx.x] = s[255];
}

__global__ void k_scanB(int* bsum, int nb) {
    int tid = threadIdx.x;   // 64 threads, nb <= 64
    int v = (tid < nb) ? bsum[tid] : 0;
    int orig = v;
    for (int off = 1; off < 64; off <<= 1) {
        int y = __shfl_up(v, off);
        if (tid >= off) v += y;
    }
    if (tid < nb) bsum[tid] = v - orig;   // exclusive block offsets
}

__global__ void k_scanC(int* __restrict__ row_start, const int* __restrict__ bsum,
                        int* __restrict__ cursor) {
    int i = blockIdx.x * 256 + threadIdx.x;
    if (i < N_NODES) {
        int rs = row_start[i] + bsum[i >> 10];
        row_start[i] = rs;
        cursor[i] = rs;
    }
}

__global__ void k_fill(const int* __restrict__ src, const int* __restrict__ dst,
                       int* cursor, int* __restrict__ csr) {
    int i = blockIdx.x * 256 + threadIdx.x;
    if (i >= N_EDGES + N_NODES) return;
    int s, d;
    if (i < N_EDGES) { s = src[i]; d = dst[i]; }
    else             { s = d = i - N_EDGES; }   // self-loops
    int slot = atomicAdd(&cursor[d], 1);
    csr[slot] = s;
}

// ---------------------------------------------------------------------------
// K5: per-node aggregation + skip + LN + ELU.
// 2 nodes per wave (32 lanes each, uint2 = 4 cols/lane) -> 512 B per load
// instruction; batch-4 unrolled gathers for 4-deep MLP; tail edges are
// weight-masked (clamped index keeps addresses valid).
// ---------------------------------------------------------------------------
__global__ __launch_bounds__(256) void k_agg(
    const uint2* __restrict__ h2,   // bf16 pairs, [N][32] uint2
    const float* __restrict__ z0,
    const float* __restrict__ a_src, const float* __restrict__ a_dst,
    const int* __restrict__ row_start, const int* __restrict__ counts,
    const int* __restrict__ csr,
    const float* __restrict__ gamma, const float* __restrict__ beta,
    float* __restrict__ out)
{
    const int tid = threadIdx.x;
    const int lane = tid & 63;
    const int l = lane & 31;                 // lane within node-half
    const int n = blockIdx.x * 8 + ((tid >> 6) << 1) + (lane >> 5);
    const int head = l >> 2;                 // cols 4l..4l+3 share a head

    const float adn = a_dst[n * 8 + head];
    const int rs = row_start[n];
    const int cnt = counts[n];               // >= 1 (self-loop)

    float d_acc = 0.f, a0 = 0.f, a1 = 0.f, a2 = 0.f, a3 = 0.f;
    for (int i = 0; i < cnt; i += 4) {
        int s[4]; float ae[4], mk[4]; uint2 hp[4];
#pragma unroll
        for (int j = 0; j < 4; j++) {
            const int e = i + j;
            const int ec = (e < cnt) ? e : (cnt - 1);
            mk[j] = (e < cnt) ? 1.f : 0.f;
            s[j] = csr[rs + ec];
        }
#pragma unroll
        for (int j = 0; j < 4; j++) ae[j] = a_src[s[j] * 8 + head];
#pragma unroll
        for (int j = 0; j < 4; j++) hp[j] = h2[(size_t)s[j] * 32 + l];
#pragma unroll
        for (int j = 0; j < 4; j++) {
            float e = ae[j] + adn;
            e = (e > 0.f) ? e : 0.2f * e;      // leaky_relu(0.2)
            const float wgt = __expf(e) * mk[j];
            d_acc += wgt;
            a0 += wgt * bf2f(hp[j].x & 0xffffu);
            a1 += wgt * bf2f(hp[j].x >> 16);
            a2 += wgt * bf2f(hp[j].y & 0xffffu);
            a3 += wgt * bf2f(hp[j].y >> 16);
        }
    }
    const float inv = 1.0f / d_acc;
    const float4 zv = *(const float4*)(z0 + (size_t)n * HC + l * 4);
    float y0 = a0 * inv + zv.x;
    float y1 = a1 * inv + zv.y;
    float y2 = a2 * inv + zv.z;
    float y3 = a3 * inv + zv.w;

    // LayerNorm over 128 cols (32-lane half-wave reduce)
    float ss = y0 + y1 + y2 + y3;
#pragma unroll
    for (int off = 1; off < 32; off <<= 1) ss += __shfl_xor(ss, off);
    const float mu = ss * (1.0f / 128.0f);
    const float d0 = y0 - mu, d1 = y1 - mu, d2 = y2 - mu, d3 = y3 - mu;
    float vs = d0 * d0 + d1 * d1 + d2 * d2 + d3 * d3;
#pragma unroll
    for (int off = 1; off < 32; off <<= 1) vs += __shfl_xor(vs, off);
    const float rstd = rsqrtf(vs * (1.0f / 128.0f) + 1e-5f);

    const float4 gv = *(const float4*)(gamma + l * 4);
    const float4 bv = *(const float4*)(beta + l * 4);
    float o0 = d0 * rstd * gv.x + bv.x;
    float o1 = d1 * rstd * gv.y + bv.y;
    float o2 = d2 * rstd * gv.z + bv.z;
    float o3 = d3 * rstd * gv.w + bv.w;
    o0 = (o0 > 0.f) ? o0 : (__expf(o0) - 1.0f);   // ELU
    o1 = (o1 > 0.f) ? o1 : (__expf(o1) - 1.0f);
    o2 = (o2 > 0.f) ? o2 : (__expf(o2) - 1.0f);
    o3 = (o3 > 0.f) ? o3 : (__expf(o3) - 1.0f);

    *(float4*)(out + (size_t)n * HC + l * 4) = make_float4(o0, o1, o2, o3);
}

// ---------------------------------------------------------------------------
extern "C" void kernel_launch(void* const* d_in, const int* in_sizes, int n_in,
                              void* d_out, int out_size, void* d_ws, size_t ws_size,
                              hipStream_t stream) {
    const float* x   = (const float*)d_in[0];
    const int*   ei  = (const int*)d_in[1];
    const float* Wg  = (const float*)d_in[2];
    const float* as_ = (const float*)d_in[3];
    const float* ad_ = (const float*)d_in[4];
    const float* bg  = (const float*)d_in[5];
    const float* Wsk = (const float*)d_in[6];
    const float* gm  = (const float*)d_in[7];
    const float* bt  = (const float*)d_in[8];
    float* out = (float*)d_out;

    // workspace layout (bytes), ~45.7 MB total
    char* wsb = (char*)d_ws;
    unsigned short* h_bf  = (unsigned short*)wsb;            // [N][128] bf16
    float*          z0    = (float*)(wsb + 12800000);        // [N][128] f32
    float*          a_src = (float*)(wsb + 38400000);        // [N][8]
    float*          a_dst = (float*)(wsb + 40000000);        // [N][8]
    unsigned short* Bfrag = (unsigned short*)(wsb + 41600000); // 64 KB
    int*   counts = (int*)(wsb + 41665536);
    int*   row_st = counts + 50048;
    int*   cursor = row_st + 50048;
    int*   bsum   = cursor + 50048;
    int*   csr    = bsum + 256;                              // 850000 ints

    const int* src = ei;
    const int* dst = ei + N_EDGES;

    k_prep  <<<196, 256, 0, stream>>>(Wg, Wsk, Bfrag, counts);
    k_linear<<<(N_NODES + 63) / 64, 256, 0, stream>>>(x, Bfrag, as_, ad_, bg,
                                                      h_bf, z0, a_src, a_dst);
    k_count <<<(N_EDGES + 255) / 256, 256, 0, stream>>>(dst, counts);
    k_scanA <<<49, 256, 0, stream>>>(counts, row_st, bsum);
    k_scanB <<<1, 64, 0, stream>>>(bsum, 49);
    k_scanC <<<(N_NODES + 255) / 256, 256, 0, stream>>>(row_st, bsum, cursor);
    k_fill  <<<(N_EDGES + N_NODES + 255) / 256, 256, 0, stream>>>(src, dst, cursor, csr);
    k_agg   <<<N_NODES / 8, 256, 0, stream>>>((const uint2*)h_bf, z0,
                                              a_src, a_dst, row_st, counts, csr,
                                              gm, bt, out);
}